// Round 12
// baseline (182.482 us; speedup 1.0000x reference)
//
#include <hip/hip_runtime.h>
#include <hip/hip_bf16.h>
#include <stdint.h>

#define B_ 4
#define N_ 4096
#define D_ 64
#define K_ 16

// ---------------- workspace layout (float-element offsets) ----------------
static const size_t OFS_WQA1  = 0;                      // Wq@A1      [64x64]
static const size_t OFS_WKA1  = 4096;                   // Wk@A1      [64x64]
static const size_t OFS_WCOMB = 8192;                   // [c][dd] dd<64: P2@A1, dd>=64: P2   [64x128]
static const size_t OFS_C1    = 16384;                  // p2b@A1 + a1b  [64]
static const size_t OFS_QA1   = 16448;                  // x@WqA1     [B*N*64]
static const size_t OFS_KA1   = OFS_QA1 + (size_t)B_*N_*64;
static const size_t OFS_V     = OFS_KA1 + (size_t)B_*N_*64;
static const size_t OFS_IDX   = OFS_V   + (size_t)B_*N_*64;           // int [B*N*16]
static const size_t OFS_POS4  = OFS_IDX + (size_t)B_*N_*16;           // float4 [B*N] (byte%16==0)
static const size_t OFS_BF16  = OFS_POS4 + (size_t)B_*N_*4;           // ushort: wcombT[128][64], a2T[64][64] (12288 ush = 6144 fl)
static const size_t OFS_PBF   = OFS_BF16 + 6144;                      // ushort: Wcat^T frag layout [192][64]

typedef __attribute__((ext_vector_type(8))) short short8;
typedef __attribute__((ext_vector_type(4))) float floatx4;

__device__ __forceinline__ unsigned short f2bf(float f) {
    __hip_bfloat16 h = __float2bfloat16(f);
    return *reinterpret_cast<unsigned short*>(&h);
}

__device__ __forceinline__ unsigned long long bsortu64(unsigned long long v, int l) {
#pragma unroll
    for (int k = 2; k <= 64; k <<= 1) {
#pragma unroll
        for (int j = k >> 1; j > 0; j >>= 1) {
            unsigned long long o = __shfl_xor(v, j, 64);
            unsigned long long mn = v < o ? v : o;
            unsigned long long mx = v < o ? o : v;
            v = ((((l & j) == 0) == ((l & k) == 0))) ? mn : mx;
        }
    }
    return v;
}

// ---------------- launch 1: precompute (+bf16 proj weights) | pos4 ----------------
__global__ __launch_bounds__(256) void k_pre(
        const float* __restrict__ Wq, const float* __restrict__ Wk,
        const float* __restrict__ Wv,
        const float* __restrict__ P2, const float* __restrict__ A1,
        const float* __restrict__ p2b, const float* __restrict__ a1b,
        const float* __restrict__ pos, float* __restrict__ ws) {
    int blk = blockIdx.x;
    unsigned short* pbf = (unsigned short*)(ws + OFS_PBF);
    if (blk < 65) {
        int i = blk * 256 + threadIdx.x;
        if (i < 4096) {
            int c = i >> 6, d = i & 63;
            float s = 0.f;
            for (int e = 0; e < 64; ++e) s = fmaf(Wq[c*64+e], A1[e*64+d], s);
            ws[OFS_WQA1 + i] = s;
            pbf[d*64 + c] = f2bf(s);
        } else if (i < 8192) {
            int j = i - 4096; int c = j >> 6, d = j & 63;
            float s = 0.f;
            for (int e = 0; e < 64; ++e) s = fmaf(Wk[c*64+e], A1[e*64+d], s);
            ws[OFS_WKA1 + j] = s;
            pbf[(64+d)*64 + c] = f2bf(s);
        } else if (i < 16384) {
            int j = i - 8192; int c = j >> 7, dd = j & 127;
            float s;
            if (dd < 64) { s = 0.f; for (int e = 0; e < 64; ++e) s = fmaf(P2[c*64+e], A1[e*64+dd], s); }
            else s = P2[c*64 + (dd - 64)];
            ws[OFS_WCOMB + j] = s;
        } else if (i < 16448) {
            int d = i - 16384;
            float s = a1b[d];
            for (int e = 0; e < 64; ++e) s = fmaf(p2b[e], A1[e*64+d], s);
            ws[OFS_C1 + d] = s;
        }
    } else if (blk < 81) {
        int i = (blk - 65) * 256 + threadIdx.x;    // 4096 elems
        int c = i >> 6, d = i & 63;
        pbf[(128+d)*64 + c] = f2bf(Wv[c*64+d]);
    } else {
        int i = (blk - 81) * 256 + threadIdx.x;    // 64 blocks -> 16384 points
        float px = pos[(size_t)i*3+0], py = pos[(size_t)i*3+1], pz = pos[(size_t)i*3+2];
        float sq = fmaf(pz, pz, fmaf(py, py, px*px));
        ((float4*)(ws + OFS_POS4))[i] = make_float4(px, py, pz, sq);
    }
}

// ---------------- launch 2: MFMA projection  x[16384x64] @ Wcat[64x192] -------
__global__ __launch_bounds__(256) void k_projm(const float* __restrict__ x,
                                               const float* __restrict__ A2,
                                               float* __restrict__ ws) {
    __shared__ unsigned short xT[64*72];     // A-tile, stride 72
    __shared__ unsigned short wTs[192*72];   // B-frags, stride 72
    const int t = threadIdx.x;
    if (blockIdx.x >= 256) {
        int i = ((int)blockIdx.x - 256) * 256 + t;   // 48 blocks -> 12288
        unsigned short* wbf = (unsigned short*)(ws + OFS_BF16);
        if (i < 8192) {
            int c = i >> 7, dd = i & 127;
            wbf[dd*64 + c] = f2bf(ws[OFS_WCOMB + i]);
        } else {
            int j = i - 8192; int e = j >> 6, d = j & 63;
            wbf[8192 + d*64 + e] = f2bf(A2[j]);
        }
        return;
    }
    const unsigned short* pbf = (const unsigned short*)(ws + OFS_PBF);
    const int g0 = (int)blockIdx.x * 64;

#pragma unroll
    for (int k = 0; k < 6; ++k) {
        int id  = t + 256*k;
        int row = id >> 3, cir = id & 7;
        uint4 vv = *(const uint4*)(pbf + row*64 + cir*8);
        *(uint4*)&wTs[row*72 + cir*8] = vv;
    }
    {
        int r = t >> 2, qd = t & 3;
        const float* src = x + (size_t)(g0 + r)*64 + qd*16;
        unsigned short hb[16];
#pragma unroll
        for (int u = 0; u < 16; ++u) hb[u] = f2bf(src[u]);
        *(uint4*)&xT[r*72 + qd*16]     = *(uint4*)&hb[0];
        *(uint4*)&xT[r*72 + qd*16 + 8] = *(uint4*)&hb[8];
    }
    __syncthreads();

    const int w = t >> 6, l = t & 63, lr = l & 15, q = l >> 4;
    floatx4 acc[12];
#pragma unroll
    for (int j = 0; j < 12; ++j) acc[j] = (floatx4){0.f, 0.f, 0.f, 0.f};
#pragma unroll
    for (int kb = 0; kb < 2; ++kb) {
        short8 a = *(const short8*)&xT[(16*w + lr)*72 + 32*kb + 8*q];
#pragma unroll
        for (int j = 0; j < 12; ++j) {
            short8 bfr = *(const short8*)&wTs[(16*j + lr)*72 + 32*kb + 8*q];
            acc[j] = __builtin_amdgcn_mfma_f32_16x16x32_bf16(a, bfr, acc[j], 0, 0, 0);
        }
    }
    float* qA1 = ws + OFS_QA1;
    float* kA1 = ws + OFS_KA1;
    float* vws = ws + OFS_V;
#pragma unroll
    for (int j = 0; j < 12; ++j) {
        int col = 16*j + lr;
        float* dst = (col < 64) ? qA1 : (col < 128 ? kA1 : vws);
        int c2 = col & 63;
#pragma unroll
        for (int r = 0; r < 4; ++r) {
            int grow = g0 + 16*w + 4*q + r;
            dst[(size_t)grow*64 + c2] = acc[j][r];
        }
    }
}

// ---------------- launch 3: exact threshold-filter kNN (512 thr, 8 q/blk) -------
__global__ __launch_bounds__(512) void k_knn(float* __restrict__ ws) {
    __shared__ float4 tile[2048];                 // 32 KB (half of one batch)
    __shared__ unsigned long long sbuf[8*128];    // 8 KB survivor buffers
    const float4* pos4 = (const float4*)(ws + OFS_POS4);
    int* idx = (int*)(ws + OFS_IDX);
    const int t = threadIdx.x;
    const int l = t & 63, wv = t >> 6;            // wv in 0..7
    const int b = (int)(blockIdx.x >> 9);
    const int q = ((int)blockIdx.x & 511) * 8 + wv;
    const size_t grow = (size_t)b * N_ + q;
    const float4* pb = pos4 + (size_t)b * N_;

    float4 qp = pos4[grow];
    float dst0[32];
    float mn = 1e30f;

#pragma unroll
    for (int i = 0; i < 4; ++i) tile[t + 512*i] = pb[t + 512*i];
    __syncthreads();
#pragma unroll 8
    for (int i = 0; i < 32; ++i) {
        float4 cd = tile[i*64 + l];
        float dot = fmaf(qp.z, cd.z, fmaf(qp.y, cd.y, qp.x*cd.x));
        float d = fmaxf(fmaf(-2.f, dot, qp.w + cd.w), 0.f);
        dst0[i] = d;
        mn = fminf(mn, d);
    }
    __syncthreads();
#pragma unroll
    for (int i = 0; i < 4; ++i) tile[t + 512*i] = pb[2048 + t + 512*i];
    __syncthreads();
#pragma unroll 8
    for (int i = 0; i < 32; ++i) {
        float4 cd = tile[i*64 + l];
        float dot = fmaf(qp.z, cd.z, fmaf(qp.y, cd.y, qp.x*cd.x));
        float d = fmaxf(fmaf(-2.f, dot, qp.w + cd.w), 0.f);
        mn = fminf(mn, d);
    }

    float v = mn;
#pragma unroll
    for (int k = 2; k <= 64; k <<= 1) {
#pragma unroll
        for (int j = k >> 1; j > 0; j >>= 1) {
            float o = __shfl_xor(v, j, 64);
            float mnv = fminf(v, o), mxv = fmaxf(v, o);
            v = ((((l & j) == 0) == ((l & k) == 0))) ? mnv : mxv;
        }
    }
    float tau = __shfl(v, 15, 64);

    unsigned long long* sb = sbuf + wv*128;
    const unsigned long long lmask = (1ull << l) - 1ull;
    int cnt = 0;
#pragma unroll 8
    for (int i = 0; i < 32; ++i) {
        bool pred = (dst0[i] <= tau);
        unsigned long long m = __ballot(pred);
        if (pred) {
            int pos2 = cnt + __popcll(m & lmask);
            if (pos2 < 128)
                sb[pos2] = ((unsigned long long)__float_as_uint(dst0[i]) << 32)
                           | (unsigned)(i*64 + l);
        }
        cnt += (int)__popcll(m);
    }
#pragma unroll 4
    for (int i = 0; i < 32; ++i) {
        float4 cd = tile[i*64 + l];
        float dot = fmaf(qp.z, cd.z, fmaf(qp.y, cd.y, qp.x*cd.x));
        float d = fmaxf(fmaf(-2.f, dot, qp.w + cd.w), 0.f);
        bool pred = (d <= tau);
        unsigned long long m = __ballot(pred);
        if (pred) {
            int pos2 = cnt + __popcll(m & lmask);
            if (pos2 < 128)
                sb[pos2] = ((unsigned long long)__float_as_uint(d) << 32)
                           | (unsigned)(2048 + i*64 + l);
        }
        cnt += (int)__popcll(m);
    }
    if (cnt > 128) cnt = 128;

    unsigned long long pk = (l < cnt) ? sb[l] : ~0ull;
    pk = bsortu64(pk, l);
    if (cnt > 64) {
        unsigned long long w2 = (64 + l < cnt) ? sb[64 + l] : ~0ull;
        w2 = bsortu64(w2, l);
        unsigned long long bb = __shfl(w2, (l - 16) & 63, 64);
        unsigned long long nv = (l < 16) ? pk : ((l < 32) ? bb : ~0ull);
        pk = bsortu64(nv, l);
    }
    if (l < 16) idx[grow*16 + l] = (int)(pk & 0xffffffffu);
}

// ---------------- launch 4: fused per-neighbor MLPs + softmax + agg + out ------
// LDS diet: a2T fragments live in registers (global load at top, hidden by
// setup+MFMA1); relb/mrow/aggb overlay one 2 KB scratch (barrier-separated).
// LDS = 18432(wT) + 18432(abuf) + 2048 = 38912 B -> 4 blocks/CU (16 waves).
__global__ __launch_bounds__(256) void k_attn(
    const float* __restrict__ x, const float* __restrict__ pos,
    const float* __restrict__ P1, const float* __restrict__ p1b,
    const float* __restrict__ p2b, const float* __restrict__ a2b,
    const float* __restrict__ Wf,
    const float* __restrict__ bff, const float* __restrict__ ws,
    float* __restrict__ out) {

    __shared__ unsigned short wT[128*72];      // wcombT fragments, stride 72
    __shared__ unsigned short abuf[128*72];    // h1 then h2, stride 72
    __shared__ float scratch[512];             // relb[384] + mrow[128] -> aggb[512]

    float* relb = scratch;                     // [128][3]
    int*   mrow = (int*)(scratch + 384);       // [128]
    float* aggb = scratch;                     // [8][64] (after mrow dead)

    const int t  = threadIdx.x;
    const int g0 = blockIdx.x * 8;
    const int b  = g0 >> 12;
    const float* qA1 = ws + OFS_QA1;
    const float* kA1 = ws + OFS_KA1;
    const float* vws = ws + OFS_V;
    const float* c1  = ws + OFS_C1;
    const int* idx = (const int*)(ws + OFS_IDX);
    const unsigned short* wbf = (const unsigned short*)(ws + OFS_BF16);

    const int w = t >> 6, l = t & 63, lr = l & 15, q = l >> 4;

    // ---- a2T B-fragments -> registers (latency hidden behind setup+MFMA1) ----
    short8 a2frag[2][4];
    {
        const unsigned short* a2g = wbf + 8192;
#pragma unroll
        for (int kb = 0; kb < 2; ++kb)
#pragma unroll
            for (int j = 0; j < 4; ++j)
                a2frag[kb][j] = *(const short8*)&a2g[(16*j + lr)*64 + 32*kb + 8*q];
    }

    // ---- stage wT into LDS: 128 rows x 8 chunks(16B) = 4 chunks/thread ----
#pragma unroll
    for (int k = 0; k < 4; ++k) {
        int id  = t + 256*k;
        int row = id >> 3, cir = id & 7;
        uint4 vv = *(const uint4*)(wbf + row*64 + cir*8);
        *(uint4*)&wT[row*72 + cir*8] = vv;
    }

    if (t < 128) {
        int p = t >> 4, k = t & 15;
        int ng = g0 + p;
        int m  = idx[(size_t)ng*16 + k];
        int mg = b * N_ + m;
        mrow[t] = mg;
        relb[t*3+0] = pos[(size_t)ng*3+0] - pos[(size_t)mg*3+0];
        relb[t*3+1] = pos[(size_t)ng*3+1] - pos[(size_t)mg*3+1];
        relb[t*3+2] = pos[(size_t)ng*3+2] - pos[(size_t)mg*3+2];
    }
    __syncthreads();

    // ---- prefetch kA1 gathers + (qA1+c1) — hidden behind h1-MLP and MFMA1 ----
    float kpre[2][4][4];
    float qpre[2][4];
#pragma unroll
    for (int i = 0; i < 2; ++i) {
        int ng = g0 + 2*w + i;
#pragma unroll
        for (int j = 0; j < 4; ++j) {
            int col = 16*j + lr;
            qpre[i][j] = qA1[(size_t)ng*64 + col] + c1[col];
#pragma unroll
            for (int r = 0; r < 4; ++r) {
                int row = 32*w + 16*i + 4*q + r;
                kpre[i][j][r] = kA1[(size_t)mrow[row]*64 + col];
            }
        }
    }

    // ---- h1 = relu(rel @ P1 + p1b) -> abuf (bf16) ----
    {
        int d = t & 63, r0 = t >> 6;
        float w0 = P1[d], w1 = P1[64+d], w2 = P1[128+d], bb = p1b[d];
#pragma unroll
        for (int jj = 0; jj < 32; ++jj) {
            int r = r0 + jj*4;
            float h = fmaf(relb[r*3+2], w2, fmaf(relb[r*3+1], w1, fmaf(relb[r*3+0], w0, bb)));
            abuf[r*72 + d] = f2bf(fmaxf(h, 0.f));
        }
    }
    __syncthreads();

    // ---- MFMA1: h1[128x64] @ [P2A1 | P2] ----
    floatx4 acc1[2][8];
#pragma unroll
    for (int i = 0; i < 2; ++i)
#pragma unroll
        for (int j = 0; j < 8; ++j) acc1[i][j] = (floatx4){0.f, 0.f, 0.f, 0.f};
#pragma unroll
    for (int kb = 0; kb < 2; ++kb) {
        short8 a0 = *(const short8*)&abuf[(32*w      + lr)*72 + 32*kb + 8*q];
        short8 a1 = *(const short8*)&abuf[(32*w + 16 + lr)*72 + 32*kb + 8*q];
#pragma unroll
        for (int j = 0; j < 8; ++j) {
            short8 bfr = *(const short8*)&wT[(16*j + lr)*72 + 32*kb + 8*q];
            acc1[0][j] = __builtin_amdgcn_mfma_f32_16x16x32_bf16(a0, bfr, acc1[0][j], 0, 0, 0);
            acc1[1][j] = __builtin_amdgcn_mfma_f32_16x16x32_bf16(a1, bfr, acc1[1][j], 0, 0, 0);
        }
    }
    __syncthreads();

    // ---- epilogue1: t1 = acc + (qA1[n]+c1) - kA1[m], h2 = relu -> abuf ----
#pragma unroll
    for (int i = 0; i < 2; ++i) {
#pragma unroll
        for (int j = 0; j < 4; ++j) {
            int col = 16*j + lr;
            float qv = qpre[i][j];
#pragma unroll
            for (int r = 0; r < 4; ++r) {
                int row = 32*w + 16*i + 4*q + r;
                float t1 = acc1[i][j][r] + qv - kpre[i][j][r];
                abuf[row*72 + col] = f2bf(fmaxf(t1, 0.f));
            }
        }
    }

    // ---- prefetch v gathers (last use of mrow) — hidden behind MFMA2 ----
    float vpre[2][4][4];
#pragma unroll
    for (int i = 0; i < 2; ++i)
#pragma unroll
        for (int j = 0; j < 4; ++j) {
            int col = 16*j + lr;
#pragma unroll
            for (int r = 0; r < 4; ++r) {
                int row = 32*w + 16*i + 4*q + r;
                vpre[i][j][r] = vws[(size_t)mrow[row]*64 + col];
            }
        }
    __syncthreads();   // after this barrier mrow/relb are dead -> aggb may reuse

    // ---- MFMA2: h2 @ A2 (B from registers) ----
    floatx4 acc2[2][4];
#pragma unroll
    for (int i = 0; i < 2; ++i)
#pragma unroll
        for (int j = 0; j < 4; ++j) acc2[i][j] = (floatx4){0.f, 0.f, 0.f, 0.f};
#pragma unroll
    for (int kb = 0; kb < 2; ++kb) {
        short8 a0 = *(const short8*)&abuf[(32*w      + lr)*72 + 32*kb + 8*q];
        short8 a1 = *(const short8*)&abuf[(32*w + 16 + lr)*72 + 32*kb + 8*q];
#pragma unroll
        for (int j = 0; j < 4; ++j) {
            acc2[0][j] = __builtin_amdgcn_mfma_f32_16x16x32_bf16(a0, a2frag[kb][j], acc2[0][j], 0, 0, 0);
            acc2[1][j] = __builtin_amdgcn_mfma_f32_16x16x32_bf16(a1, a2frag[kb][j], acc2[1][j], 0, 0, 0);
        }
    }

    // ---- stage E: softmax over K=16, aggregate ----
#pragma unroll
    for (int i = 0; i < 2; ++i) {
#pragma unroll
        for (int j = 0; j < 4; ++j) {
            int col = 16*j + lr;
            float a2bv = a2b[col], p2bv = p2b[col];
            float L[4];
#pragma unroll
            for (int r = 0; r < 4; ++r) L[r] = acc2[i][j][r] + a2bv;
            float mx = fmaxf(fmaxf(L[0], L[1]), fmaxf(L[2], L[3]));
            mx = fmaxf(mx, __shfl_xor(mx, 16, 64));
            mx = fmaxf(mx, __shfl_xor(mx, 32, 64));
            float ssum = 0.f, part = 0.f;
#pragma unroll
            for (int r = 0; r < 4; ++r) {
                float e = __expf((L[r] - mx) * 0.125f);
                ssum += e;
                float wv = vpre[i][j][r] + (acc1[i][4+j][r] + p2bv);
                part = fmaf(e, wv, part);
            }
            ssum += __shfl_xor(ssum, 16, 64);
            ssum += __shfl_xor(ssum, 32, 64);
            part += __shfl_xor(part, 16, 64);
            part += __shfl_xor(part, 32, 64);
            float agg = part / ssum;
            if (q == 0) aggb[(2*w + i)*64 + col] = agg;
        }
    }
    __syncthreads();

    // ---- stage F: out = agg @ Wf + bf + x ----
    {
        int d = t & 63;
        int p0 = t >> 6;
#pragma unroll
        for (int pp = p0; pp < 8; pp += 4) {
            float s = bff[d];
#pragma unroll 8
            for (int c = 0; c < 64; ++c) s = fmaf(aggb[pp*64 + c], Wf[c*64 + d], s);
            int g = g0 + pp;
            out[(size_t)g*64 + d] = s + x[(size_t)g*64 + d];
        }
    }
}

// ---------------- launch ----------------
extern "C" void kernel_launch(void* const* d_in, const int* in_sizes, int n_in,
                              void* d_out, int out_size, void* d_ws, size_t ws_size,
                              hipStream_t stream) {
    const float* x   = (const float*)d_in[0];
    const float* pos = (const float*)d_in[1];
    const float* Wq  = (const float*)d_in[2];
    const float* Wk  = (const float*)d_in[3];
    const float* Wv  = (const float*)d_in[4];
    const float* P1  = (const float*)d_in[5];
    const float* p1b = (const float*)d_in[6];
    const float* P2  = (const float*)d_in[7];
    const float* p2b = (const float*)d_in[8];
    const float* A1  = (const float*)d_in[9];
    const float* a1b = (const float*)d_in[10];
    const float* A2  = (const float*)d_in[11];
    const float* a2b = (const float*)d_in[12];
    const float* Wf  = (const float*)d_in[13];
    const float* bf  = (const float*)d_in[14];
    float* out = (float*)d_out;
    float* ws  = (float*)d_ws;

    hipLaunchKernelGGL(k_pre,   dim3(145),  dim3(256), 0, stream,
                       Wq, Wk, Wv, P2, A1, p2b, a1b, pos, ws);
    hipLaunchKernelGGL(k_projm, dim3(304),  dim3(256), 0, stream, x, A2, ws);
    hipLaunchKernelGGL(k_knn,   dim3(2048), dim3(512), 0, stream, ws);
    hipLaunchKernelGGL(k_attn,  dim3(2048), dim3(256), 0, stream,
                       x, pos, P1, p1b, p2b, a2b, Wf, bf, ws, out);
}

// Round 13
// 169.536 us; speedup vs baseline: 1.0764x; 1.0764x over previous
//
#include <hip/hip_runtime.h>
#include <hip/hip_bf16.h>
#include <stdint.h>

#define B_ 4
#define N_ 4096
#define D_ 64
#define K_ 16

// ---------------- workspace layout (float-element offsets) ----------------
static const size_t OFS_WQA1  = 0;                      // Wq@A1      [64x64]
static const size_t OFS_WKA1  = 4096;                   // Wk@A1      [64x64]
static const size_t OFS_WCOMB = 8192;                   // [c][dd] dd<64: P2@A1, dd>=64: P2   [64x128]
static const size_t OFS_C1    = 16384;                  // p2b@A1 + a1b  [64]
static const size_t OFS_QA1   = 16448;                  // x@WqA1     [B*N*64]
static const size_t OFS_KA1   = OFS_QA1 + (size_t)B_*N_*64;
static const size_t OFS_V     = OFS_KA1 + (size_t)B_*N_*64;
static const size_t OFS_IDX   = OFS_V   + (size_t)B_*N_*64;           // int [B*N*16]
static const size_t OFS_POS4  = OFS_IDX + (size_t)B_*N_*16;           // float4 [B*N] (byte%16==0)
static const size_t OFS_BF16  = OFS_POS4 + (size_t)B_*N_*4;           // ushort: wcombT[128][64], a2T[64][64] (12288 ush)
static const size_t OFS_PBF   = OFS_BF16 + 6144;                      // ushort: Wcat^T frag layout [192][64]
static const size_t OFS_WFB   = OFS_PBF + 6144;                       // ushort: Wf^T frag layout [64][64]

typedef __attribute__((ext_vector_type(8))) short short8;
typedef __attribute__((ext_vector_type(4))) float floatx4;

__device__ __forceinline__ unsigned short f2bf(float f) {
    __hip_bfloat16 h = __float2bfloat16(f);
    return *reinterpret_cast<unsigned short*>(&h);
}

__device__ __forceinline__ unsigned long long bsortu64(unsigned long long v, int l) {
#pragma unroll
    for (int k = 2; k <= 64; k <<= 1) {
#pragma unroll
        for (int j = k >> 1; j > 0; j >>= 1) {
            unsigned long long o = __shfl_xor(v, j, 64);
            unsigned long long mn = v < o ? v : o;
            unsigned long long mx = v < o ? o : v;
            v = ((((l & j) == 0) == ((l & k) == 0))) ? mn : mx;
        }
    }
    return v;
}

// ---------------- launch 1: precompute (+bf16 weights) | pos4 ----------------
// [0,65): WQA1/WKA1/WCOMB/C1 (+bf16 frags)  [65,81): Wv  [81,97): Wf  [97,161): pos4
__global__ __launch_bounds__(256) void k_pre(
        const float* __restrict__ Wq, const float* __restrict__ Wk,
        const float* __restrict__ Wv, const float* __restrict__ Wf,
        const float* __restrict__ P2, const float* __restrict__ A1,
        const float* __restrict__ p2b, const float* __restrict__ a1b,
        const float* __restrict__ pos, float* __restrict__ ws) {
    int blk = blockIdx.x;
    unsigned short* pbf = (unsigned short*)(ws + OFS_PBF);
    if (blk < 65) {
        int i = blk * 256 + threadIdx.x;
        if (i < 4096) {
            int c = i >> 6, d = i & 63;
            float s = 0.f;
            for (int e = 0; e < 64; ++e) s = fmaf(Wq[c*64+e], A1[e*64+d], s);
            ws[OFS_WQA1 + i] = s;
            pbf[d*64 + c] = f2bf(s);
        } else if (i < 8192) {
            int j = i - 4096; int c = j >> 6, d = j & 63;
            float s = 0.f;
            for (int e = 0; e < 64; ++e) s = fmaf(Wk[c*64+e], A1[e*64+d], s);
            ws[OFS_WKA1 + j] = s;
            pbf[(64+d)*64 + c] = f2bf(s);
        } else if (i < 16384) {
            int j = i - 8192; int c = j >> 7, dd = j & 127;
            float s;
            if (dd < 64) { s = 0.f; for (int e = 0; e < 64; ++e) s = fmaf(P2[c*64+e], A1[e*64+dd], s); }
            else s = P2[c*64 + (dd - 64)];
            ws[OFS_WCOMB + j] = s;
        } else if (i < 16448) {
            int d = i - 16384;
            float s = a1b[d];
            for (int e = 0; e < 64; ++e) s = fmaf(p2b[e], A1[e*64+d], s);
            ws[OFS_C1 + d] = s;
        }
    } else if (blk < 81) {
        int i = (blk - 65) * 256 + threadIdx.x;    // 4096 elems
        int c = i >> 6, d = i & 63;
        pbf[(128+d)*64 + c] = f2bf(Wv[c*64+d]);
    } else if (blk < 97) {
        int i = (blk - 81) * 256 + threadIdx.x;    // 4096 elems
        int c = i >> 6, d = i & 63;
        ((unsigned short*)(ws + OFS_WFB))[d*64 + c] = f2bf(Wf[c*64+d]);
    } else {
        int i = (blk - 97) * 256 + threadIdx.x;    // 64 blocks -> 16384 points
        float px = pos[(size_t)i*3+0], py = pos[(size_t)i*3+1], pz = pos[(size_t)i*3+2];
        float sq = fmaf(pz, pz, fmaf(py, py, px*px));
        ((float4*)(ws + OFS_POS4))[i] = make_float4(px, py, pz, sq);
    }
}

// ---------------- launch 2: MFMA projection  x[16384x64] @ Wcat[64x192] -------
__global__ __launch_bounds__(256) void k_projm(const float* __restrict__ x,
                                               const float* __restrict__ A2,
                                               float* __restrict__ ws) {
    __shared__ unsigned short xT[64*72];     // A-tile, stride 72
    __shared__ unsigned short wTs[192*72];   // B-frags, stride 72
    const int t = threadIdx.x;
    if (blockIdx.x >= 256) {
        int i = ((int)blockIdx.x - 256) * 256 + t;   // 48 blocks -> 12288
        unsigned short* wbf = (unsigned short*)(ws + OFS_BF16);
        if (i < 8192) {
            int c = i >> 7, dd = i & 127;
            wbf[dd*64 + c] = f2bf(ws[OFS_WCOMB + i]);
        } else {
            int j = i - 8192; int e = j >> 6, d = j & 63;
            wbf[8192 + d*64 + e] = f2bf(A2[j]);
        }
        return;
    }
    const unsigned short* pbf = (const unsigned short*)(ws + OFS_PBF);
    const int g0 = (int)blockIdx.x * 64;

#pragma unroll
    for (int k = 0; k < 6; ++k) {
        int id  = t + 256*k;
        int row = id >> 3, cir = id & 7;
        uint4 vv = *(const uint4*)(pbf + row*64 + cir*8);
        *(uint4*)&wTs[row*72 + cir*8] = vv;
    }
    {
        int r = t >> 2, qd = t & 3;
        const float* src = x + (size_t)(g0 + r)*64 + qd*16;
        unsigned short hb[16];
#pragma unroll
        for (int u = 0; u < 16; ++u) hb[u] = f2bf(src[u]);
        *(uint4*)&xT[r*72 + qd*16]     = *(uint4*)&hb[0];
        *(uint4*)&xT[r*72 + qd*16 + 8] = *(uint4*)&hb[8];
    }
    __syncthreads();

    const int w = t >> 6, l = t & 63, lr = l & 15, q = l >> 4;
    floatx4 acc[12];
#pragma unroll
    for (int j = 0; j < 12; ++j) acc[j] = (floatx4){0.f, 0.f, 0.f, 0.f};
#pragma unroll
    for (int kb = 0; kb < 2; ++kb) {
        short8 a = *(const short8*)&xT[(16*w + lr)*72 + 32*kb + 8*q];
#pragma unroll
        for (int j = 0; j < 12; ++j) {
            short8 bfr = *(const short8*)&wTs[(16*j + lr)*72 + 32*kb + 8*q];
            acc[j] = __builtin_amdgcn_mfma_f32_16x16x32_bf16(a, bfr, acc[j], 0, 0, 0);
        }
    }
    float* qA1 = ws + OFS_QA1;
    float* kA1 = ws + OFS_KA1;
    float* vws = ws + OFS_V;
#pragma unroll
    for (int j = 0; j < 12; ++j) {
        int col = 16*j + lr;
        float* dst = (col < 64) ? qA1 : (col < 128 ? kA1 : vws);
        int c2 = col & 63;
#pragma unroll
        for (int r = 0; r < 4; ++r) {
            int grow = g0 + 16*w + 4*q + r;
            dst[(size_t)grow*64 + c2] = acc[j][r];
        }
    }
}

// ---------------- launch 3: exact threshold-filter kNN (512 thr, 8 q/blk) -------
__global__ __launch_bounds__(512) void k_knn(float* __restrict__ ws) {
    __shared__ float4 tile[2048];                 // 32 KB (half of one batch)
    __shared__ unsigned long long sbuf[8*128];    // 8 KB survivor buffers
    const float4* pos4 = (const float4*)(ws + OFS_POS4);
    int* idx = (int*)(ws + OFS_IDX);
    const int t = threadIdx.x;
    const int l = t & 63, wv = t >> 6;            // wv in 0..7
    const int b = (int)(blockIdx.x >> 9);
    const int q = ((int)blockIdx.x & 511) * 8 + wv;
    const size_t grow = (size_t)b * N_ + q;
    const float4* pb = pos4 + (size_t)b * N_;

    float4 qp = pos4[grow];
    float dst0[32];
    float mn = 1e30f;

#pragma unroll
    for (int i = 0; i < 4; ++i) tile[t + 512*i] = pb[t + 512*i];
    __syncthreads();
#pragma unroll 8
    for (int i = 0; i < 32; ++i) {
        float4 cd = tile[i*64 + l];
        float dot = fmaf(qp.z, cd.z, fmaf(qp.y, cd.y, qp.x*cd.x));
        float d = fmaxf(fmaf(-2.f, dot, qp.w + cd.w), 0.f);
        dst0[i] = d;
        mn = fminf(mn, d);
    }
    __syncthreads();
#pragma unroll
    for (int i = 0; i < 4; ++i) tile[t + 512*i] = pb[2048 + t + 512*i];
    __syncthreads();
#pragma unroll 8
    for (int i = 0; i < 32; ++i) {
        float4 cd = tile[i*64 + l];
        float dot = fmaf(qp.z, cd.z, fmaf(qp.y, cd.y, qp.x*cd.x));
        float d = fmaxf(fmaf(-2.f, dot, qp.w + cd.w), 0.f);
        mn = fminf(mn, d);
    }

    float v = mn;
#pragma unroll
    for (int k = 2; k <= 64; k <<= 1) {
#pragma unroll
        for (int j = k >> 1; j > 0; j >>= 1) {
            float o = __shfl_xor(v, j, 64);
            float mnv = fminf(v, o), mxv = fmaxf(v, o);
            v = ((((l & j) == 0) == ((l & k) == 0))) ? mnv : mxv;
        }
    }
    float tau = __shfl(v, 15, 64);

    unsigned long long* sb = sbuf + wv*128;
    const unsigned long long lmask = (1ull << l) - 1ull;
    int cnt = 0;
#pragma unroll 8
    for (int i = 0; i < 32; ++i) {
        bool pred = (dst0[i] <= tau);
        unsigned long long m = __ballot(pred);
        if (pred) {
            int pos2 = cnt + __popcll(m & lmask);
            if (pos2 < 128)
                sb[pos2] = ((unsigned long long)__float_as_uint(dst0[i]) << 32)
                           | (unsigned)(i*64 + l);
        }
        cnt += (int)__popcll(m);
    }
#pragma unroll 4
    for (int i = 0; i < 32; ++i) {
        float4 cd = tile[i*64 + l];
        float dot = fmaf(qp.z, cd.z, fmaf(qp.y, cd.y, qp.x*cd.x));
        float d = fmaxf(fmaf(-2.f, dot, qp.w + cd.w), 0.f);
        bool pred = (d <= tau);
        unsigned long long m = __ballot(pred);
        if (pred) {
            int pos2 = cnt + __popcll(m & lmask);
            if (pos2 < 128)
                sb[pos2] = ((unsigned long long)__float_as_uint(d) << 32)
                           | (unsigned)(2048 + i*64 + l);
        }
        cnt += (int)__popcll(m);
    }
    if (cnt > 128) cnt = 128;

    unsigned long long pk = (l < cnt) ? sb[l] : ~0ull;
    pk = bsortu64(pk, l);
    if (cnt > 64) {
        unsigned long long w2 = (64 + l < cnt) ? sb[64 + l] : ~0ull;
        w2 = bsortu64(w2, l);
        unsigned long long bb = __shfl(w2, (l - 16) & 63, 64);
        unsigned long long nv = (l < 16) ? pk : ((l < 32) ? bb : ~0ull);
        pk = bsortu64(nv, l);
    }
    if (l < 16) idx[grow*16 + l] = (int)(pk & 0xffffffffu);
}

// ---------------- launch 4: fused per-neighbor MLPs + softmax + agg + out ------
// R11 structure (84 VGPR, 3 blocks/CU) + MFMA stage F:
// softmax writes agg (bf16, A-frag layout) into abuf rows 0..7;
// out = agg @ Wf via 2 MFMAs/wave with Wf^T frags prefetched at vpre time.
__global__ __launch_bounds__(256) void k_attn(
    const float* __restrict__ x, const float* __restrict__ pos,
    const float* __restrict__ P1, const float* __restrict__ p1b,
    const float* __restrict__ p2b, const float* __restrict__ a2b,
    const float* __restrict__ bff, const float* __restrict__ ws,
    float* __restrict__ out) {

    __shared__ unsigned short wT[128*72];      // wcombT fragments, stride 72
    __shared__ unsigned short a2T[64*72];      // A2^T fragments, stride 72
    __shared__ unsigned short abuf[128*72];    // h1 / h2 / agg, stride 72
    __shared__ float relb[128*4];
    __shared__ int   mrow[128];

    const int t  = threadIdx.x;
    const int g0 = blockIdx.x * 8;
    const int b  = g0 >> 12;
    const float* qA1 = ws + OFS_QA1;
    const float* kA1 = ws + OFS_KA1;
    const float* vws = ws + OFS_V;
    const float* c1  = ws + OFS_C1;
    const int* idx = (const int*)(ws + OFS_IDX);
    const unsigned short* wbf = (const unsigned short*)(ws + OFS_BF16);
    const unsigned short* wfb = (const unsigned short*)(ws + OFS_WFB);

#pragma unroll
    for (int k = 0; k < 6; ++k) {
        int id  = t + 256*k;
        int row = id >> 3, cir = id & 7;
        uint4 vv = *(const uint4*)(wbf + row*64 + cir*8);
        if (row < 128) *(uint4*)&wT[row*72 + cir*8] = vv;
        else           *(uint4*)&a2T[(row-128)*72 + cir*8] = vv;
    }

    if (t < 128) {
        int p = t >> 4, k = t & 15;
        int ng = g0 + p;
        int m  = idx[(size_t)ng*16 + k];
        int mg = b * N_ + m;
        mrow[t] = mg;
        relb[t*4+0] = pos[(size_t)ng*3+0] - pos[(size_t)mg*3+0];
        relb[t*4+1] = pos[(size_t)ng*3+1] - pos[(size_t)mg*3+1];
        relb[t*4+2] = pos[(size_t)ng*3+2] - pos[(size_t)mg*3+2];
    }
    __syncthreads();

    const int w = t >> 6, l = t & 63, lr = l & 15, q = l >> 4;

    // ---- prefetch kA1 gathers + (qA1+c1) — hidden behind h1-MLP and MFMA1 ----
    float kpre[2][4][4];
    float qpre[2][4];
#pragma unroll
    for (int i = 0; i < 2; ++i) {
        int ng = g0 + 2*w + i;
#pragma unroll
        for (int j = 0; j < 4; ++j) {
            int col = 16*j + lr;
            qpre[i][j] = qA1[(size_t)ng*64 + col] + c1[col];
#pragma unroll
            for (int r = 0; r < 4; ++r) {
                int row = 32*w + 16*i + 4*q + r;
                kpre[i][j][r] = kA1[(size_t)mrow[row]*64 + col];
            }
        }
    }

    // ---- h1 = relu(rel @ P1 + p1b) -> abuf (bf16) ----
    {
        int d = t & 63, r0 = t >> 6;
        float w0 = P1[d], w1 = P1[64+d], w2 = P1[128+d], bb = p1b[d];
#pragma unroll
        for (int jj = 0; jj < 32; ++jj) {
            int r = r0 + jj*4;
            float h = fmaf(relb[r*4+2], w2, fmaf(relb[r*4+1], w1, fmaf(relb[r*4+0], w0, bb)));
            abuf[r*72 + d] = f2bf(fmaxf(h, 0.f));
        }
    }
    __syncthreads();

    // ---- MFMA1: h1[128x64] @ [P2A1 | P2] ----
    floatx4 acc1[2][8];
#pragma unroll
    for (int i = 0; i < 2; ++i)
#pragma unroll
        for (int j = 0; j < 8; ++j) acc1[i][j] = (floatx4){0.f, 0.f, 0.f, 0.f};
#pragma unroll
    for (int kb = 0; kb < 2; ++kb) {
        short8 a0 = *(const short8*)&abuf[(32*w      + lr)*72 + 32*kb + 8*q];
        short8 a1 = *(const short8*)&abuf[(32*w + 16 + lr)*72 + 32*kb + 8*q];
#pragma unroll
        for (int j = 0; j < 8; ++j) {
            short8 bfr = *(const short8*)&wT[(16*j + lr)*72 + 32*kb + 8*q];
            acc1[0][j] = __builtin_amdgcn_mfma_f32_16x16x32_bf16(a0, bfr, acc1[0][j], 0, 0, 0);
            acc1[1][j] = __builtin_amdgcn_mfma_f32_16x16x32_bf16(a1, bfr, acc1[1][j], 0, 0, 0);
        }
    }
    __syncthreads();

    // ---- epilogue1: t1 = acc + (qA1[n]+c1) - kA1[m], h2 = relu -> abuf ----
#pragma unroll
    for (int i = 0; i < 2; ++i) {
#pragma unroll
        for (int j = 0; j < 4; ++j) {
            int col = 16*j + lr;
            float qv = qpre[i][j];
#pragma unroll
            for (int r = 0; r < 4; ++r) {
                int row = 32*w + 16*i + 4*q + r;
                float t1 = acc1[i][j][r] + qv - kpre[i][j][r];
                abuf[row*72 + col] = f2bf(fmaxf(t1, 0.f));
            }
        }
    }

    // ---- prefetch v gathers + Wf^T frags — hidden behind MFMA2+softmax ----
    float vpre[2][4][4];
#pragma unroll
    for (int i = 0; i < 2; ++i)
#pragma unroll
        for (int j = 0; j < 4; ++j) {
            int col = 16*j + lr;
#pragma unroll
            for (int r = 0; r < 4; ++r) {
                int row = 32*w + 16*i + 4*q + r;
                vpre[i][j][r] = vws[(size_t)mrow[row]*64 + col];
            }
        }
    short8 wffrag[2];
#pragma unroll
    for (int kb = 0; kb < 2; ++kb)
        wffrag[kb] = *(const short8*)&wfb[(16*w + lr)*64 + 32*kb + 8*q];
    __syncthreads();

    // ---- MFMA2: h2 @ A2 ----
    floatx4 acc2[2][4];
#pragma unroll
    for (int i = 0; i < 2; ++i)
#pragma unroll
        for (int j = 0; j < 4; ++j) acc2[i][j] = (floatx4){0.f, 0.f, 0.f, 0.f};
#pragma unroll
    for (int kb = 0; kb < 2; ++kb) {
        short8 a0 = *(const short8*)&abuf[(32*w      + lr)*72 + 32*kb + 8*q];
        short8 a1 = *(const short8*)&abuf[(32*w + 16 + lr)*72 + 32*kb + 8*q];
#pragma unroll
        for (int j = 0; j < 4; ++j) {
            short8 bfr = *(const short8*)&a2T[(16*j + lr)*72 + 32*kb + 8*q];
            acc2[0][j] = __builtin_amdgcn_mfma_f32_16x16x32_bf16(a0, bfr, acc2[0][j], 0, 0, 0);
            acc2[1][j] = __builtin_amdgcn_mfma_f32_16x16x32_bf16(a1, bfr, acc2[1][j], 0, 0, 0);
        }
    }
    __syncthreads();   // all waves done reading abuf (h2) before agg overwrites

    // ---- stage E: softmax over K=16, aggregate; agg -> abuf rows 0..7 (bf16) ----
#pragma unroll
    for (int i = 0; i < 2; ++i) {
#pragma unroll
        for (int j = 0; j < 4; ++j) {
            int col = 16*j + lr;
            float a2bv = a2b[col], p2bv = p2b[col];
            float L[4];
#pragma unroll
            for (int r = 0; r < 4; ++r) L[r] = acc2[i][j][r] + a2bv;
            float mx = fmaxf(fmaxf(L[0], L[1]), fmaxf(L[2], L[3]));
            mx = fmaxf(mx, __shfl_xor(mx, 16, 64));
            mx = fmaxf(mx, __shfl_xor(mx, 32, 64));
            float ssum = 0.f, part = 0.f;
#pragma unroll
            for (int r = 0; r < 4; ++r) {
                float e = __expf((L[r] - mx) * 0.125f);
                ssum += e;
                float wv = vpre[i][j][r] + (acc1[i][4+j][r] + p2bv);
                part = fmaf(e, wv, part);
            }
            ssum += __shfl_xor(ssum, 16, 64);
            ssum += __shfl_xor(ssum, 32, 64);
            part += __shfl_xor(part, 16, 64);
            part += __shfl_xor(part, 32, 64);
            float agg = part / ssum;
            if (q == 0) abuf[(2*w + i)*72 + col] = f2bf(agg);
        }
    }
    __syncthreads();

    // ---- stage F: out = agg @ Wf + bf + x  (MFMA, rows 8..15 garbage unused) ----
    {
        floatx4 accF = (floatx4){0.f, 0.f, 0.f, 0.f};
#pragma unroll
        for (int kb = 0; kb < 2; ++kb) {
            short8 afr = *(const short8*)&abuf[lr*72 + 32*kb + 8*q];
            accF = __builtin_amdgcn_mfma_f32_16x16x32_bf16(afr, wffrag[kb], accF, 0, 0, 0);
        }
        if (q < 2) {
            int col = 16*w + lr;
            float bv = bff[col];
#pragma unroll
            for (int r = 0; r < 4; ++r) {
                int g = g0 + 4*q + r;
                out[(size_t)g*64 + col] = accF[r] + bv + x[(size_t)g*64 + col];
            }
        }
    }
}

// ---------------- launch ----------------
extern "C" void kernel_launch(void* const* d_in, const int* in_sizes, int n_in,
                              void* d_out, int out_size, void* d_ws, size_t ws_size,
                              hipStream_t stream) {
    const float* x   = (const float*)d_in[0];
    const float* pos = (const float*)d_in[1];
    const float* Wq  = (const float*)d_in[2];
    const float* Wk  = (const float*)d_in[3];
    const float* Wv  = (const float*)d_in[4];
    const float* P1  = (const float*)d_in[5];
    const float* p1b = (const float*)d_in[6];
    const float* P2  = (const float*)d_in[7];
    const float* p2b = (const float*)d_in[8];
    const float* A1  = (const float*)d_in[9];
    const float* a1b = (const float*)d_in[10];
    const float* A2  = (const float*)d_in[11];
    const float* a2b = (const float*)d_in[12];
    const float* Wf  = (const float*)d_in[13];
    const float* bf  = (const float*)d_in[14];
    float* out = (float*)d_out;
    float* ws  = (float*)d_ws;

    hipLaunchKernelGGL(k_pre,   dim3(161),  dim3(256), 0, stream,
                       Wq, Wk, Wv, Wf, P2, A1, p2b, a1b, pos, ws);
    hipLaunchKernelGGL(k_projm, dim3(304),  dim3(256), 0, stream, x, A2, ws);
    hipLaunchKernelGGL(k_knn,   dim3(2048), dim3(512), 0, stream, ws);
    hipLaunchKernelGGL(k_attn,  dim3(2048), dim3(256), 0, stream,
                       x, pos, P1, p1b, p2b, a2b, bf, ws, out);
}

// Round 14
// 169.409 us; speedup vs baseline: 1.0772x; 1.0008x over previous
//
#include <hip/hip_runtime.h>
#include <hip/hip_bf16.h>
#include <stdint.h>

#define B_ 4
#define N_ 4096
#define D_ 64
#define K_ 16

// ---------------- workspace layout (float-element offsets) ----------------
static const size_t OFS_WQA1  = 0;                      // Wq@A1      [64x64]
static const size_t OFS_WKA1  = 4096;                   // Wk@A1      [64x64]
static const size_t OFS_WCOMB = 8192;                   // [c][dd] dd<64: P2@A1, dd>=64: P2   [64x128]
static const size_t OFS_C1    = 16384;                  // p2b@A1 + a1b  [64]
static const size_t OFS_QA1   = 16448;                  // x@WqA1     [B*N*64]
static const size_t OFS_KA1   = OFS_QA1 + (size_t)B_*N_*64;
static const size_t OFS_V     = OFS_KA1 + (size_t)B_*N_*64;
static const size_t OFS_IDX   = OFS_V   + (size_t)B_*N_*64;           // int [B*N*16]
static const size_t OFS_POS4  = OFS_IDX + (size_t)B_*N_*16;           // float4 [B*N] (byte%16==0)
static const size_t OFS_BF16  = OFS_POS4 + (size_t)B_*N_*4;           // ushort: wcombT[128][64], a2T[64][64] (12288 ush)
static const size_t OFS_PBF   = OFS_BF16 + 6144;                      // ushort: Wcat^T frag layout [192][64]
static const size_t OFS_WFB   = OFS_PBF + 6144;                       // ushort: Wf^T frag layout [64][64]

typedef __attribute__((ext_vector_type(8))) short short8;
typedef __attribute__((ext_vector_type(4))) float floatx4;

__device__ __forceinline__ unsigned short f2bf(float f) {
    __hip_bfloat16 h = __float2bfloat16(f);
    return *reinterpret_cast<unsigned short*>(&h);
}

__device__ __forceinline__ unsigned long long bsortu64(unsigned long long v, int l) {
#pragma unroll
    for (int k = 2; k <= 64; k <<= 1) {
#pragma unroll
        for (int j = k >> 1; j > 0; j >>= 1) {
            unsigned long long o = __shfl_xor(v, j, 64);
            unsigned long long mn = v < o ? v : o;
            unsigned long long mx = v < o ? o : v;
            v = ((((l & j) == 0) == ((l & k) == 0))) ? mn : mx;
        }
    }
    return v;
}

// dual interleaved bitonic sorts (two independent chains overlap latency)
__device__ __forceinline__ void bsortu64x2(unsigned long long& a, unsigned long long& b, int l) {
#pragma unroll
    for (int k = 2; k <= 64; k <<= 1) {
#pragma unroll
        for (int j = k >> 1; j > 0; j >>= 1) {
            unsigned long long oa = __shfl_xor(a, j, 64);
            unsigned long long ob = __shfl_xor(b, j, 64);
            bool up = (((l & j) == 0) == ((l & k) == 0));
            unsigned long long mna = a < oa ? a : oa, mxa = a < oa ? oa : a;
            unsigned long long mnb = b < ob ? b : ob, mxb = b < ob ? ob : b;
            a = up ? mna : mxa;
            b = up ? mnb : mxb;
        }
    }
}

// ---------------- launch 1: precompute (+bf16 weights) | pos4 ----------------
// [0,65): WQA1/WKA1/WCOMB/C1 (+bf16 frags)  [65,81): Wv  [81,97): Wf  [97,161): pos4
__global__ __launch_bounds__(256) void k_pre(
        const float* __restrict__ Wq, const float* __restrict__ Wk,
        const float* __restrict__ Wv, const float* __restrict__ Wf,
        const float* __restrict__ P2, const float* __restrict__ A1,
        const float* __restrict__ p2b, const float* __restrict__ a1b,
        const float* __restrict__ pos, float* __restrict__ ws) {
    int blk = blockIdx.x;
    unsigned short* pbf = (unsigned short*)(ws + OFS_PBF);
    if (blk < 65) {
        int i = blk * 256 + threadIdx.x;
        if (i < 4096) {
            int c = i >> 6, d = i & 63;
            float s = 0.f;
            for (int e = 0; e < 64; ++e) s = fmaf(Wq[c*64+e], A1[e*64+d], s);
            ws[OFS_WQA1 + i] = s;
            pbf[d*64 + c] = f2bf(s);
        } else if (i < 8192) {
            int j = i - 4096; int c = j >> 6, d = j & 63;
            float s = 0.f;
            for (int e = 0; e < 64; ++e) s = fmaf(Wk[c*64+e], A1[e*64+d], s);
            ws[OFS_WKA1 + j] = s;
            pbf[(64+d)*64 + c] = f2bf(s);
        } else if (i < 16384) {
            int j = i - 8192; int c = j >> 7, dd = j & 127;
            float s;
            if (dd < 64) { s = 0.f; for (int e = 0; e < 64; ++e) s = fmaf(P2[c*64+e], A1[e*64+dd], s); }
            else s = P2[c*64 + (dd - 64)];
            ws[OFS_WCOMB + j] = s;
        } else if (i < 16448) {
            int d = i - 16384;
            float s = a1b[d];
            for (int e = 0; e < 64; ++e) s = fmaf(p2b[e], A1[e*64+d], s);
            ws[OFS_C1 + d] = s;
        }
    } else if (blk < 81) {
        int i = (blk - 65) * 256 + threadIdx.x;    // 4096 elems
        int c = i >> 6, d = i & 63;
        pbf[(128+d)*64 + c] = f2bf(Wv[c*64+d]);
    } else if (blk < 97) {
        int i = (blk - 81) * 256 + threadIdx.x;    // 4096 elems
        int c = i >> 6, d = i & 63;
        ((unsigned short*)(ws + OFS_WFB))[d*64 + c] = f2bf(Wf[c*64+d]);
    } else {
        int i = (blk - 97) * 256 + threadIdx.x;    // 64 blocks -> 16384 points
        float px = pos[(size_t)i*3+0], py = pos[(size_t)i*3+1], pz = pos[(size_t)i*3+2];
        float sq = fmaf(pz, pz, fmaf(py, py, px*px));
        ((float4*)(ws + OFS_POS4))[i] = make_float4(px, py, pz, sq);
    }
}

// ---------------- launch 2: MFMA projection  x[16384x64] @ Wcat[64x192] -------
__global__ __launch_bounds__(256) void k_projm(const float* __restrict__ x,
                                               const float* __restrict__ A2,
                                               float* __restrict__ ws) {
    __shared__ unsigned short xT[64*72];     // A-tile, stride 72
    __shared__ unsigned short wTs[192*72];   // B-frags, stride 72
    const int t = threadIdx.x;
    if (blockIdx.x >= 256) {
        int i = ((int)blockIdx.x - 256) * 256 + t;   // 48 blocks -> 12288
        unsigned short* wbf = (unsigned short*)(ws + OFS_BF16);
        if (i < 8192) {
            int c = i >> 7, dd = i & 127;
            wbf[dd*64 + c] = f2bf(ws[OFS_WCOMB + i]);
        } else {
            int j = i - 8192; int e = j >> 6, d = j & 63;
            wbf[8192 + d*64 + e] = f2bf(A2[j]);
        }
        return;
    }
    const unsigned short* pbf = (const unsigned short*)(ws + OFS_PBF);
    const int g0 = (int)blockIdx.x * 64;

#pragma unroll
    for (int k = 0; k < 6; ++k) {
        int id  = t + 256*k;
        int row = id >> 3, cir = id & 7;
        uint4 vv = *(const uint4*)(pbf + row*64 + cir*8);
        *(uint4*)&wTs[row*72 + cir*8] = vv;
    }
    {
        int r = t >> 2, qd = t & 3;
        const float* src = x + (size_t)(g0 + r)*64 + qd*16;
        unsigned short hb[16];
#pragma unroll
        for (int u = 0; u < 16; ++u) hb[u] = f2bf(src[u]);
        *(uint4*)&xT[r*72 + qd*16]     = *(uint4*)&hb[0];
        *(uint4*)&xT[r*72 + qd*16 + 8] = *(uint4*)&hb[8];
    }
    __syncthreads();

    const int w = t >> 6, l = t & 63, lr = l & 15, q = l >> 4;
    floatx4 acc[12];
#pragma unroll
    for (int j = 0; j < 12; ++j) acc[j] = (floatx4){0.f, 0.f, 0.f, 0.f};
#pragma unroll
    for (int kb = 0; kb < 2; ++kb) {
        short8 a = *(const short8*)&xT[(16*w + lr)*72 + 32*kb + 8*q];
#pragma unroll
        for (int j = 0; j < 12; ++j) {
            short8 bfr = *(const short8*)&wTs[(16*j + lr)*72 + 32*kb + 8*q];
            acc[j] = __builtin_amdgcn_mfma_f32_16x16x32_bf16(a, bfr, acc[j], 0, 0, 0);
        }
    }
    float* qA1 = ws + OFS_QA1;
    float* kA1 = ws + OFS_KA1;
    float* vws = ws + OFS_V;
#pragma unroll
    for (int j = 0; j < 12; ++j) {
        int col = 16*j + lr;
        float* dst = (col < 64) ? qA1 : (col < 128 ? kA1 : vws);
        int c2 = col & 63;
#pragma unroll
        for (int r = 0; r < 4; ++r) {
            int grow = g0 + 16*w + 4*q + r;
            dst[(size_t)grow*64 + c2] = acc[j][r];
        }
    }
}

// ---------------- launch 3: exact threshold-filter kNN --------------------------
// 512 thr, 8 waves, TWO queries per wave: one tile read feeds both queries'
// distance chains (DS reads/query 96 -> 48), and the two bitonic sorts
// interleave (independent shuffle chains overlap latency).
__global__ __launch_bounds__(512) void k_knn(float* __restrict__ ws) {
    __shared__ float4 tile[2048];                  // 32 KB (half of one batch)
    __shared__ unsigned long long sbuf[16*128];    // 16 KB (2 survivor bufs / wave)
    const float4* pos4 = (const float4*)(ws + OFS_POS4);
    int* idx = (int*)(ws + OFS_IDX);
    const int t = threadIdx.x;
    const int l = t & 63, wv = t >> 6;             // wv in 0..7
    const int b = (int)(blockIdx.x >> 8);          // 1024 blocks: 4 batches x 256
    const int q0 = ((int)(blockIdx.x & 255)) * 16 + 2*wv;
    const size_t g0r = (size_t)b * N_ + q0;
    const float4* pb = pos4 + (size_t)b * N_;

    float4 qa = pos4[g0r];
    float4 qb = pos4[g0r + 1];
    float d0[32], d1[32];
    float mn0 = 1e30f, mn1 = 1e30f;

    // ---- stage half0 + pass1 (both queries' distances -> registers) ----
#pragma unroll
    for (int i = 0; i < 4; ++i) tile[t + 512*i] = pb[t + 512*i];
    __syncthreads();
#pragma unroll 8
    for (int i = 0; i < 32; ++i) {
        float4 cd = tile[i*64 + l];
        float dotA = fmaf(qa.z, cd.z, fmaf(qa.y, cd.y, qa.x*cd.x));
        float dA = fmaxf(fmaf(-2.f, dotA, qa.w + cd.w), 0.f);
        float dotB = fmaf(qb.z, cd.z, fmaf(qb.y, cd.y, qb.x*cd.x));
        float dB = fmaxf(fmaf(-2.f, dotB, qb.w + cd.w), 0.f);
        d0[i] = dA; d1[i] = dB;
        mn0 = fminf(mn0, dA); mn1 = fminf(mn1, dB);
    }
    __syncthreads();
    // ---- stage half1 + pass1 (min only; tile stays resident for pass2) ----
#pragma unroll
    for (int i = 0; i < 4; ++i) tile[t + 512*i] = pb[2048 + t + 512*i];
    __syncthreads();
#pragma unroll 8
    for (int i = 0; i < 32; ++i) {
        float4 cd = tile[i*64 + l];
        float dotA = fmaf(qa.z, cd.z, fmaf(qa.y, cd.y, qa.x*cd.x));
        mn0 = fminf(mn0, fmaxf(fmaf(-2.f, dotA, qa.w + cd.w), 0.f));
        float dotB = fmaf(qb.z, cd.z, fmaf(qb.y, cd.y, qb.x*cd.x));
        mn1 = fminf(mn1, fmaxf(fmaf(-2.f, dotB, qb.w + cd.w), 0.f));
    }

    // ---- dual tau = 16th smallest lane-min (interleaved bitonic) ----
    float v0 = mn0, v1 = mn1;
#pragma unroll
    for (int k = 2; k <= 64; k <<= 1) {
#pragma unroll
        for (int j = k >> 1; j > 0; j >>= 1) {
            float o0 = __shfl_xor(v0, j, 64);
            float o1 = __shfl_xor(v1, j, 64);
            bool up = (((l & j) == 0) == ((l & k) == 0));
            v0 = up ? fminf(v0, o0) : fmaxf(v0, o0);
            v1 = up ? fminf(v1, o1) : fmaxf(v1, o1);
        }
    }
    float tau0 = __shfl(v0, 15, 64);
    float tau1 = __shfl(v1, 15, 64);

    // ---- pass2: ballot-compact survivors for both queries ----
    unsigned long long* sb0 = sbuf + wv*256;
    unsigned long long* sb1 = sb0 + 128;
    const unsigned long long lmask = (1ull << l) - 1ull;
    int cnt0 = 0, cnt1 = 0;
#pragma unroll 8
    for (int i = 0; i < 32; ++i) {
        bool p0 = (d0[i] <= tau0);
        unsigned long long m0 = __ballot(p0);
        if (p0) {
            int pp = cnt0 + __popcll(m0 & lmask);
            if (pp < 128)
                sb0[pp] = ((unsigned long long)__float_as_uint(d0[i]) << 32) | (unsigned)(i*64 + l);
        }
        cnt0 += (int)__popcll(m0);
        bool p1 = (d1[i] <= tau1);
        unsigned long long m1 = __ballot(p1);
        if (p1) {
            int pp = cnt1 + __popcll(m1 & lmask);
            if (pp < 128)
                sb1[pp] = ((unsigned long long)__float_as_uint(d1[i]) << 32) | (unsigned)(i*64 + l);
        }
        cnt1 += (int)__popcll(m1);
    }
#pragma unroll 4
    for (int i = 0; i < 32; ++i) {
        float4 cd = tile[i*64 + l];
        float dotA = fmaf(qa.z, cd.z, fmaf(qa.y, cd.y, qa.x*cd.x));
        float dA = fmaxf(fmaf(-2.f, dotA, qa.w + cd.w), 0.f);
        float dotB = fmaf(qb.z, cd.z, fmaf(qb.y, cd.y, qb.x*cd.x));
        float dB = fmaxf(fmaf(-2.f, dotB, qb.w + cd.w), 0.f);
        bool p0 = (dA <= tau0);
        unsigned long long m0 = __ballot(p0);
        if (p0) {
            int pp = cnt0 + __popcll(m0 & lmask);
            if (pp < 128)
                sb0[pp] = ((unsigned long long)__float_as_uint(dA) << 32) | (unsigned)(2048 + i*64 + l);
        }
        cnt0 += (int)__popcll(m0);
        bool p1 = (dB <= tau1);
        unsigned long long m1 = __ballot(p1);
        if (p1) {
            int pp = cnt1 + __popcll(m1 & lmask);
            if (pp < 128)
                sb1[pp] = ((unsigned long long)__float_as_uint(dB) << 32) | (unsigned)(2048 + i*64 + l);
        }
        cnt1 += (int)__popcll(m1);
    }
    if (cnt0 > 128) cnt0 = 128;
    if (cnt1 > 128) cnt1 = 128;

    // ---- pass3: dual interleaved survivor sort, write top-16 each ----
    unsigned long long pk0 = (l < cnt0) ? sb0[l] : ~0ull;
    unsigned long long pk1 = (l < cnt1) ? sb1[l] : ~0ull;
    bsortu64x2(pk0, pk1, l);
    if (cnt0 > 64) {   // astronomically rare
        unsigned long long w2 = (64 + l < cnt0) ? sb0[64 + l] : ~0ull;
        w2 = bsortu64(w2, l);
        unsigned long long bb = __shfl(w2, (l - 16) & 63, 64);
        unsigned long long nv = (l < 16) ? pk0 : ((l < 32) ? bb : ~0ull);
        pk0 = bsortu64(nv, l);
    }
    if (cnt1 > 64) {
        unsigned long long w2 = (64 + l < cnt1) ? sb1[64 + l] : ~0ull;
        w2 = bsortu64(w2, l);
        unsigned long long bb = __shfl(w2, (l - 16) & 63, 64);
        unsigned long long nv = (l < 16) ? pk1 : ((l < 32) ? bb : ~0ull);
        pk1 = bsortu64(nv, l);
    }
    if (l < 16) {
        idx[g0r*16 + l]       = (int)(pk0 & 0xffffffffu);
        idx[(g0r + 1)*16 + l] = (int)(pk1 & 0xffffffffu);
    }
}

// ---------------- launch 4: fused per-neighbor MLPs + softmax + agg + out ------
// R11 structure + MFMA stage F (R13).
__global__ __launch_bounds__(256) void k_attn(
    const float* __restrict__ x, const float* __restrict__ pos,
    const float* __restrict__ P1, const float* __restrict__ p1b,
    const float* __restrict__ p2b, const float* __restrict__ a2b,
    const float* __restrict__ bff, const float* __restrict__ ws,
    float* __restrict__ out) {

    __shared__ unsigned short wT[128*72];      // wcombT fragments, stride 72
    __shared__ unsigned short a2T[64*72];      // A2^T fragments, stride 72
    __shared__ unsigned short abuf[128*72];    // h1 / h2 / agg, stride 72
    __shared__ float relb[128*4];
    __shared__ int   mrow[128];

    const int t  = threadIdx.x;
    const int g0 = blockIdx.x * 8;
    const int b  = g0 >> 12;
    const float* qA1 = ws + OFS_QA1;
    const float* kA1 = ws + OFS_KA1;
    const float* vws = ws + OFS_V;
    const float* c1  = ws + OFS_C1;
    const int* idx = (const int*)(ws + OFS_IDX);
    const unsigned short* wbf = (const unsigned short*)(ws + OFS_BF16);
    const unsigned short* wfb = (const unsigned short*)(ws + OFS_WFB);

#pragma unroll
    for (int k = 0; k < 6; ++k) {
        int id  = t + 256*k;
        int row = id >> 3, cir = id & 7;
        uint4 vv = *(const uint4*)(wbf + row*64 + cir*8);
        if (row < 128) *(uint4*)&wT[row*72 + cir*8] = vv;
        else           *(uint4*)&a2T[(row-128)*72 + cir*8] = vv;
    }

    if (t < 128) {
        int p = t >> 4, k = t & 15;
        int ng = g0 + p;
        int m  = idx[(size_t)ng*16 + k];
        int mg = b * N_ + m;
        mrow[t] = mg;
        relb[t*4+0] = pos[(size_t)ng*3+0] - pos[(size_t)mg*3+0];
        relb[t*4+1] = pos[(size_t)ng*3+1] - pos[(size_t)mg*3+1];
        relb[t*4+2] = pos[(size_t)ng*3+2] - pos[(size_t)mg*3+2];
    }
    __syncthreads();

    const int w = t >> 6, l = t & 63, lr = l & 15, q = l >> 4;

    // ---- prefetch kA1 gathers + (qA1+c1) — hidden behind h1-MLP and MFMA1 ----
    float kpre[2][4][4];
    float qpre[2][4];
#pragma unroll
    for (int i = 0; i < 2; ++i) {
        int ng = g0 + 2*w + i;
#pragma unroll
        for (int j = 0; j < 4; ++j) {
            int col = 16*j + lr;
            qpre[i][j] = qA1[(size_t)ng*64 + col] + c1[col];
#pragma unroll
            for (int r = 0; r < 4; ++r) {
                int row = 32*w + 16*i + 4*q + r;
                kpre[i][j][r] = kA1[(size_t)mrow[row]*64 + col];
            }
        }
    }

    // ---- h1 = relu(rel @ P1 + p1b) -> abuf (bf16) ----
    {
        int d = t & 63, r0 = t >> 6;
        float w0 = P1[d], w1 = P1[64+d], w2 = P1[128+d], bb = p1b[d];
#pragma unroll
        for (int jj = 0; jj < 32; ++jj) {
            int r = r0 + jj*4;
            float h = fmaf(relb[r*4+2], w2, fmaf(relb[r*4+1], w1, fmaf(relb[r*4+0], w0, bb)));
            abuf[r*72 + d] = f2bf(fmaxf(h, 0.f));
        }
    }
    __syncthreads();

    // ---- MFMA1: h1[128x64] @ [P2A1 | P2] ----
    floatx4 acc1[2][8];
#pragma unroll
    for (int i = 0; i < 2; ++i)
#pragma unroll
        for (int j = 0; j < 8; ++j) acc1[i][j] = (floatx4){0.f, 0.f, 0.f, 0.f};
#pragma unroll
    for (int kb = 0; kb < 2; ++kb) {
        short8 a0 = *(const short8*)&abuf[(32*w      + lr)*72 + 32*kb + 8*q];
        short8 a1 = *(const short8*)&abuf[(32*w + 16 + lr)*72 + 32*kb + 8*q];
#pragma unroll
        for (int j = 0; j < 8; ++j) {
            short8 bfr = *(const short8*)&wT[(16*j + lr)*72 + 32*kb + 8*q];
            acc1[0][j] = __builtin_amdgcn_mfma_f32_16x16x32_bf16(a0, bfr, acc1[0][j], 0, 0, 0);
            acc1[1][j] = __builtin_amdgcn_mfma_f32_16x16x32_bf16(a1, bfr, acc1[1][j], 0, 0, 0);
        }
    }
    __syncthreads();

    // ---- epilogue1: t1 = acc + (qA1[n]+c1) - kA1[m], h2 = relu -> abuf ----
#pragma unroll
    for (int i = 0; i < 2; ++i) {
#pragma unroll
        for (int j = 0; j < 4; ++j) {
            int col = 16*j + lr;
            float qv = qpre[i][j];
#pragma unroll
            for (int r = 0; r < 4; ++r) {
                int row = 32*w + 16*i + 4*q + r;
                float t1 = acc1[i][j][r] + qv - kpre[i][j][r];
                abuf[row*72 + col] = f2bf(fmaxf(t1, 0.f));
            }
        }
    }

    // ---- prefetch v gathers + Wf^T frags — hidden behind MFMA2+softmax ----
    float vpre[2][4][4];
#pragma unroll
    for (int i = 0; i < 2; ++i)
#pragma unroll
        for (int j = 0; j < 4; ++j) {
            int col = 16*j + lr;
#pragma unroll
            for (int r = 0; r < 4; ++r) {
                int row = 32*w + 16*i + 4*q + r;
                vpre[i][j][r] = vws[(size_t)mrow[row]*64 + col];
            }
        }
    short8 wffrag[2];
#pragma unroll
    for (int kb = 0; kb < 2; ++kb)
        wffrag[kb] = *(const short8*)&wfb[(16*w + lr)*64 + 32*kb + 8*q];
    __syncthreads();

    // ---- MFMA2: h2 @ A2 ----
    floatx4 acc2[2][4];
#pragma unroll
    for (int i = 0; i < 2; ++i)
#pragma unroll
        for (int j = 0; j < 4; ++j) acc2[i][j] = (floatx4){0.f, 0.f, 0.f, 0.f};
#pragma unroll
    for (int kb = 0; kb < 2; ++kb) {
        short8 a0 = *(const short8*)&abuf[(32*w      + lr)*72 + 32*kb + 8*q];
        short8 a1 = *(const short8*)&abuf[(32*w + 16 + lr)*72 + 32*kb + 8*q];
#pragma unroll
        for (int j = 0; j < 4; ++j) {
            short8 bfr = *(const short8*)&a2T[(16*j + lr)*72 + 32*kb + 8*q];
            acc2[0][j] = __builtin_amdgcn_mfma_f32_16x16x32_bf16(a0, bfr, acc2[0][j], 0, 0, 0);
            acc2[1][j] = __builtin_amdgcn_mfma_f32_16x16x32_bf16(a1, bfr, acc2[1][j], 0, 0, 0);
        }
    }
    __syncthreads();   // all waves done reading abuf (h2) before agg overwrites

    // ---- stage E: softmax over K=16, aggregate; agg -> abuf rows 0..7 (bf16) ----
#pragma unroll
    for (int i = 0; i < 2; ++i) {
#pragma unroll
        for (int j = 0; j < 4; ++j) {
            int col = 16*j + lr;
            float a2bv = a2b[col], p2bv = p2b[col];
            float L[4];
#pragma unroll
            for (int r = 0; r < 4; ++r) L[r] = acc2[i][j][r] + a2bv;
            float mx = fmaxf(fmaxf(L[0], L[1]), fmaxf(L[2], L[3]));
            mx = fmaxf(mx, __shfl_xor(mx, 16, 64));
            mx = fmaxf(mx, __shfl_xor(mx, 32, 64));
            float ssum = 0.f, part = 0.f;
#pragma unroll
            for (int r = 0; r < 4; ++r) {
                float e = __expf((L[r] - mx) * 0.125f);
                ssum += e;
                float wv = vpre[i][j][r] + (acc1[i][4+j][r] + p2bv);
                part = fmaf(e, wv, part);
            }
            ssum += __shfl_xor(ssum, 16, 64);
            ssum += __shfl_xor(ssum, 32, 64);
            part += __shfl_xor(part, 16, 64);
            part += __shfl_xor(part, 32, 64);
            float agg = part / ssum;
            if (q == 0) abuf[(2*w + i)*72 + col] = f2bf(agg);
        }
    }
    __syncthreads();

    // ---- stage F: out = agg @ Wf + bf + x  (MFMA) ----
    {
        floatx4 accF = (floatx4){0.f, 0.f, 0.f, 0.f};
#pragma unroll
        for (int kb = 0; kb < 2; ++kb) {
            short8 afr = *(const short8*)&abuf[lr*72 + 32*kb + 8*q];
            accF = __builtin_amdgcn_mfma_f32_16x16x32_bf16(afr, wffrag[kb], accF, 0, 0, 0);
        }
        if (q < 2) {
            int col = 16*w + lr;
            float bv = bff[col];
#pragma unroll
            for (int r = 0; r < 4; ++r) {
                int g = g0 + 4*q + r;
                out[(size_t)g*64 + col] = accF[r] + bv + x[(size_t)g*64 + col];
            }
        }
    }
}

// ---------------- launch ----------------
extern "C" void kernel_launch(void* const* d_in, const int* in_sizes, int n_in,
                              void* d_out, int out_size, void* d_ws, size_t ws_size,
                              hipStream_t stream) {
    const float* x   = (const float*)d_in[0];
    const float* pos = (const float*)d_in[1];
    const float* Wq  = (const float*)d_in[2];
    const float* Wk  = (const float*)d_in[3];
    const float* Wv  = (const float*)d_in[4];
    const float* P1  = (const float*)d_in[5];
    const float* p1b = (const float*)d_in[6];
    const float* P2  = (const float*)d_in[7];
    const float* p2b = (const float*)d_in[8];
    const float* A1  = (const float*)d_in[9];
    const float* a1b = (const float*)d_in[10];
    const float* A2  = (const float*)d_in[11];
    const float* a2b = (const float*)d_in[12];
    const float* Wf  = (const float*)d_in[13];
    const float* bf  = (const float*)d_in[14];
    float* out = (float*)d_out;
    float* ws  = (float*)d_ws;

    hipLaunchKernelGGL(k_pre,   dim3(161),  dim3(256), 0, stream,
                       Wq, Wk, Wv, Wf, P2, A1, p2b, a1b, pos, ws);
    hipLaunchKernelGGL(k_projm, dim3(304),  dim3(256), 0, stream, x, A2, ws);
    hipLaunchKernelGGL(k_knn,   dim3(1024), dim3(512), 0, stream, ws);
    hipLaunchKernelGGL(k_attn,  dim3(2048), dim3(256), 0, stream,
                       x, pos, P1, p1b, p2b, a2b, bf, ws, out);
}